// Round 1
// baseline (32098.294 us; speedup 1.0000x reference)
//
#include <hip/hip_runtime.h>

typedef _Float16 f16;
typedef _Float16 half8 __attribute__((ext_vector_type(8)));
typedef float f32x4 __attribute__((ext_vector_type(4)));

#define T_LEN 500
#define NB 64
#define NSEQ 128
#define HID 512
#define GDIM 1024

__device__ inline float frcp(float x) {
#if __has_builtin(__builtin_amdgcn_rcpf)
  return __builtin_amdgcn_rcpf(x);
#else
  return 1.0f / x;
#endif
}
__device__ inline float fexp2(float x) {
#if __has_builtin(__builtin_amdgcn_exp2f)
  return __builtin_amdgcn_exp2f(x);
#else
  return exp2f(x);
#endif
}

// ---------------- small prep kernels ----------------

__global__ void k_cvt(const float* __restrict__ s, f16* __restrict__ d, int n) {
  int i = blockIdx.x * 256 + threadIdx.x;
  if (i < n) d[i] = (f16)s[i];
}

// w0 [1024][89] -> padded f16 [1024][96]
__global__ void k_w0pad(const float* __restrict__ w0, f16* __restrict__ d) {
  int i = blockIdx.x * 256 + threadIdx.x;
  if (i >= 1024 * 96) return;
  int row = i / 96, c = i % 96;
  d[i] = (c < 89) ? (f16)w0[row * 89 + c] : (f16)0.f;
}

// xb0 f16 [128][500][96]: s<64: x[s][t][f]; s>=64: x[s-64][499-t][f]; pad f>=89 with 0
__global__ void k_xb0(const float* __restrict__ x, f16* __restrict__ d) {
  int i = blockIdx.x * 256 + threadIdx.x;
  if (i >= 128 * 500 * 96) return;
  int f = i % 96;
  int t = (i / 96) % 500;
  int s = i / (96 * 500);
  float v = 0.f;
  if (f < 89) {
    if (s < 64) v = x[((size_t)s * 500 + t) * 89 + f];
    else        v = x[((size_t)(s - 64) * 500 + (499 - t)) * 89 + f];
  }
  d[i] = (f16)v;
}

__global__ void k_offs(const int* __restrict__ lens, int* __restrict__ offs) {
  if (threadIdx.x == 0 && blockIdx.x == 0) {
    int s = 0;
    for (int i = 0; i < 64; ++i) { offs[i] = s; s += lens[i]; }
  }
}

// ---------------- gates GEMM ----------------
// gates[t][s][n] = bias[n] + sum_k X(s,t,k) * W[n][k],  f16 out, layout [T][128][1024]
// MODE 0: X = xb0 [128][500][96], KW=96.  MODE 1: X = hs with bidir-flip rule, KW=1024.
template <int MODE>
__global__ __launch_bounds__(256) void k_gates(const f16* __restrict__ Aw,
                                               const f16* __restrict__ W16,
                                               const float* __restrict__ bias,
                                               f16* __restrict__ gates) {
  constexpr int KW = MODE ? 1024 : 96;
  const int t = blockIdx.x;
  const int nb = blockIdx.y * 128;
  const int tid = threadIdx.x;
  const int w = tid >> 6, l = tid & 63, c = l & 15, rg = l >> 4;
  const int wr = w >> 1, wc = w & 1;

  __shared__ f16 As[128 * 40];
  __shared__ f16 Bs[128 * 40];

  f32x4 acc[4][4] = {};

  const int srow = tid >> 1;
  const int seg = (tid & 1) * 16;

  for (int kb = 0; kb < KW; kb += 32) {
    const f16* pa;
    if (MODE == 0) {
      pa = Aw + ((size_t)srow * 500 + t) * 96 + kb + seg;
    } else {
      int f0 = kb + seg;
      int half = f0 >> 9;
      int col = f0 & 511;
      int s = srow;
      int seq, time;
      if (s < 64) { seq = half ? 64 + s : s;  time = half ? 499 - t : t; }
      else        { seq = half ? s : s - 64;  time = half ? t : 499 - t; }
      pa = Aw + ((size_t)seq * 500 + time) * 512 + col;
    }
    const f16* pb = W16 + (size_t)(nb + srow) * KW + kb + seg;
    half8 a0 = *(const half8*)pa;
    half8 a1 = *(const half8*)(pa + 8);
    half8 b0 = *(const half8*)pb;
    half8 b1 = *(const half8*)(pb + 8);
    __syncthreads();
    *(half8*)&As[srow * 40 + seg] = a0;
    *(half8*)&As[srow * 40 + seg + 8] = a1;
    *(half8*)&Bs[srow * 40 + seg] = b0;
    *(half8*)&Bs[srow * 40 + seg + 8] = b1;
    __syncthreads();
    half8 aF[4], bF[4];
#pragma unroll
    for (int i = 0; i < 4; ++i)
      aF[i] = *(const half8*)&As[(wr * 64 + i * 16 + c) * 40 + rg * 8];
#pragma unroll
    for (int j = 0; j < 4; ++j)
      bF[j] = *(const half8*)&Bs[(wc * 64 + j * 16 + c) * 40 + rg * 8];
#pragma unroll
    for (int i = 0; i < 4; ++i)
#pragma unroll
      for (int j = 0; j < 4; ++j)
        acc[i][j] = __builtin_amdgcn_mfma_f32_16x16x32_f16(aF[i], bF[j], acc[i][j], 0, 0, 0);
  }

#pragma unroll
  for (int j = 0; j < 4; ++j) {
    int n = nb + wc * 64 + j * 16 + c;
    float bj = bias[n];
#pragma unroll
    for (int i = 0; i < 4; ++i) {
#pragma unroll
      for (int r = 0; r < 4; ++r) {
        int m = wr * 64 + i * 16 + rg * 4 + r;
        gates[((size_t)t * 128 + m) * 1024 + n] = (f16)(acc[i][j][r] + bj);
      }
    }
  }
}

// ---------------- recurrence ----------------
// 8 WGs x 16 seqs. 16 waves; wave w owns gate cols a:[32w,32w+32), z:[512+32w,+32).
// U B-fragments resident in registers for all 500 steps. h double-buffered in LDS
// in A-fragment order; each lane keeps its 8 h values (matching its C-frag slots)
// in registers across steps.
__global__ __launch_bounds__(1024, 1) void k_rec(const f16* __restrict__ gates,
                                                 const f16* __restrict__ U,   // [1024][512] f16
                                                 f16* __restrict__ hs) {      // [128][500][512] f16
  const int sb = blockIdx.x * 16;
  const int tid = threadIdx.x;
  const int w = tid >> 6, l = tid & 63, c = l & 15, rg = l >> 4;

  __shared__ f16 hlds[2][8192];  // [buf][kt*512 + lane*8 + e]
  for (int i = tid; i < 8192; i += 1024) hlds[0][i] = (f16)0.f;

  const int n0a[4] = {32 * w, 32 * w + 16, 512 + 32 * w, 512 + 32 * w + 16};

  // Load U fragments: B[k][n] = U[n][k]; lane holds n = n0+ c, k = kt*32 + rg*8 + e
  half8 u[4][16];
#pragma unroll
  for (int nt = 0; nt < 4; ++nt) {
#pragma unroll
    for (int kt = 0; kt < 16; ++kt) {
      const f16* p = U + (size_t)(n0a[nt] + c) * 512 + kt * 32 + rg * 8;
      u[nt][kt] = *(const half8*)p;
    }
  }

  float hreg[2][4];
#pragma unroll
  for (int j = 0; j < 2; ++j)
#pragma unroll
    for (int r = 0; r < 4; ++r) hreg[j][r] = 0.f;

  // preload gates for t=0
  float gbuf[4][4];
#pragma unroll
  for (int nt = 0; nt < 4; ++nt)
#pragma unroll
    for (int r = 0; r < 4; ++r)
      gbuf[nt][r] = (float)gates[((size_t)0 * 128 + sb + rg * 4 + r) * 1024 + n0a[nt] + c];

  __syncthreads();
  int buf = 0;

  for (int t = 0; t < 500; ++t) {
    // prefetch next step's gates (reads past end at t=499 stay inside ws; unused)
    f16 gnxt[4][4];
#pragma unroll
    for (int nt = 0; nt < 4; ++nt)
#pragma unroll
      for (int r = 0; r < 4; ++r)
        gnxt[nt][r] = gates[((size_t)(t + 1) * 128 + sb + rg * 4 + r) * 1024 + n0a[nt] + c];

    f32x4 acc[4];
#pragma unroll
    for (int nt = 0; nt < 4; ++nt) {
      f32x4 a;
      a[0] = gbuf[nt][0]; a[1] = gbuf[nt][1]; a[2] = gbuf[nt][2]; a[3] = gbuf[nt][3];
      acc[nt] = a;
    }

#pragma unroll
    for (int kt = 0; kt < 16; ++kt) {
      half8 aF = *(const half8*)&hlds[buf][kt * 512 + l * 8];
#pragma unroll
      for (int nt = 0; nt < 4; ++nt)
        acc[nt] = __builtin_amdgcn_mfma_f32_16x16x32_f16(aF, u[nt][kt], acc[nt], 0, 0, 0);
    }

    // gating + h update, all lane-local. a = acc[j], z = acc[2+j]
#pragma unroll
    for (int j = 0; j < 2; ++j) {
#pragma unroll
      for (int r = 0; r < 4; ++r) {
        float av = acc[j][r];
        float zv = acc[2 + j][r];
        float zs = frcp(1.f + fexp2(-1.44269504f * zv));          // sigmoid
        float u2 = fexp2(2.88539008f * av);
        float th = 1.f - 2.f * frcp(u2 + 1.f);                    // tanh
        float hn = th + zs * (hreg[j][r] - th);                   // z*h + (1-z)*tanh
        hreg[j][r] = hn;
        int s = rg * 4 + r;
        int k = 32 * w + 16 * j + c;
        // LDS write in A-frag order: kt=w, lane' = s + 16*((2j + (c>>3))&3), e = c&7
        int lane2 = s + 16 * ((2 * j + (c >> 3)) & 3);
        hlds[buf ^ 1][w * 512 + lane2 * 8 + (c & 7)] = (f16)hn;
        hs[((size_t)(sb + s) * 500 + t) * 512 + k] = (f16)hn;
      }
    }
    // consume gbuf
#pragma unroll
    for (int nt = 0; nt < 4; ++nt)
#pragma unroll
      for (int r = 0; r < 4; ++r) gbuf[nt][r] = (float)gnxt[nt][r];

    __syncthreads();
    buf ^= 1;
  }
}

// ---------------- FC + pack ----------------
__global__ __launch_bounds__(256) void k_fc(const f16* __restrict__ hs,
                                            const f16* __restrict__ wfc,   // [72][1024] f16
                                            const float* __restrict__ bfc,
                                            const int* __restrict__ lens,
                                            const int* __restrict__ offs,
                                            float* __restrict__ out) {
  const int b = blockIdx.x, chunk = blockIdx.y;
  const int tid = threadIdx.x;
  __shared__ f16 X[16][1032];
#pragma unroll
  for (int ii = 0; ii < 8; ++ii) {
    int sg = ii * 256 + tid;
    int row = sg >> 7;
    int f = (sg & 127) * 8;
    int t = chunk * 16 + row;
    int tt = t < 500 ? t : 499;
    int half = f >> 9, col = f & 511;
    int seq = half ? 64 + b : b;
    int time = half ? 499 - tt : tt;
    *(half8*)&X[row][f] = *(const half8*)&hs[((size_t)seq * 500 + time) * 512 + col];
  }
  __syncthreads();
  int row = tid >> 4, og = tid & 15;
  int t = chunk * 16 + row;
  int len = lens[b];
  float acc[5];
#pragma unroll
  for (int j = 0; j < 5; ++j) {
    int o = j * 16 + og;
    acc[j] = (o < 72) ? bfc[o] : 0.f;
  }
  for (int k8 = 0; k8 < 128; ++k8) {
    half8 x8 = *(const half8*)&X[row][k8 * 8];
    float xf[8];
#pragma unroll
    for (int e = 0; e < 8; ++e) xf[e] = (float)x8[e];
#pragma unroll
    for (int j = 0; j < 5; ++j) {
      int o = j * 16 + og;
      int oc = o < 72 ? o : 0;
      half8 w8 = *(const half8*)&wfc[(size_t)oc * 1024 + k8 * 8];
#pragma unroll
      for (int e = 0; e < 8; ++e) acc[j] += xf[e] * (float)w8[e];
    }
  }
  if (t < 500 && t < len) {
    size_t base = ((size_t)offs[b] + t) * 72;
#pragma unroll
    for (int j = 0; j < 5; ++j) {
      int o = j * 16 + og;
      if (o < 72) out[base + o] = acc[j];
    }
  }
}

// ---------------- launcher ----------------

extern "C" void kernel_launch(void* const* d_in, const int* in_sizes, int n_in,
                              void* d_out, int out_size, void* d_ws, size_t ws_size,
                              hipStream_t stream) {
  const float* batch = (const float*)d_in[0];
  const int*   lens  = (const int*)d_in[1];
  const float* w0 = (const float*)d_in[2];
  const float* b0 = (const float*)d_in[3];
  const float* u0 = (const float*)d_in[4];
  const float* w1 = (const float*)d_in[5];
  const float* b1 = (const float*)d_in[6];
  const float* u1 = (const float*)d_in[7];
  const float* w2 = (const float*)d_in[8];
  const float* b2 = (const float*)d_in[9];
  const float* u2 = (const float*)d_in[10];
  const float* wfc = (const float*)d_in[11];
  const float* bfc = (const float*)d_in[12];
  float* out = (float*)d_out;

  char* ws = (char*)d_ws;
  // byte offsets
  const size_t GATES_OFF = 0;                  // [500][128][1024] f16 = 131,072,000
  const size_t HS_OFF    = 131072000;          // [128][500][512]  f16 =  65,536,000
  const size_t XB0_OFF   = 196608000;          // [128][500][96]   f16 =  12,288,000
  const size_t W0P_OFF   = 208896000;          // [1024][96]  f16
  const size_t W1_OFF    = 209092608;          // [1024][1024] f16
  const size_t W2_OFF    = 211189760;
  const size_t U0_OFF    = 213286912;          // [1024][512] f16
  const size_t U1_OFF    = 214335488;
  const size_t U2_OFF    = 215384064;
  const size_t WFC_OFF   = 216432640;          // [72][1024] f16
  const size_t OFFS_OFF  = 216580096;          // 64 ints

  f16* g_gates = (f16*)(ws + GATES_OFF);
  f16* g_hs    = (f16*)(ws + HS_OFF);
  f16* g_xb0   = (f16*)(ws + XB0_OFF);
  f16* g_w0p   = (f16*)(ws + W0P_OFF);
  f16* g_w1    = (f16*)(ws + W1_OFF);
  f16* g_w2    = (f16*)(ws + W2_OFF);
  f16* g_u0    = (f16*)(ws + U0_OFF);
  f16* g_u1    = (f16*)(ws + U1_OFF);
  f16* g_u2    = (f16*)(ws + U2_OFF);
  f16* g_wfc   = (f16*)(ws + WFC_OFF);
  int* g_offs  = (int*)(ws + OFFS_OFF);

  hipLaunchKernelGGL(k_offs, dim3(1), dim3(64), 0, stream, lens, g_offs);

  auto cvt = [&](const float* s, f16* d, int n) {
    hipLaunchKernelGGL(k_cvt, dim3((n + 255) / 256), dim3(256), 0, stream, s, d, n);
  };
  cvt(w1, g_w1, 1024 * 1024);
  cvt(w2, g_w2, 1024 * 1024);
  cvt(u0, g_u0, 1024 * 512);
  cvt(u1, g_u1, 1024 * 512);
  cvt(u2, g_u2, 1024 * 512);
  cvt(wfc, g_wfc, 72 * 1024);
  hipLaunchKernelGGL(k_w0pad, dim3((1024 * 96 + 255) / 256), dim3(256), 0, stream, w0, g_w0p);
  hipLaunchKernelGGL(k_xb0, dim3((128 * 500 * 96 + 255) / 256), dim3(256), 0, stream, batch, g_xb0);

  // layer 0
  hipLaunchKernelGGL((k_gates<0>), dim3(500, 8), dim3(256), 0, stream, g_xb0, g_w0p, b0, g_gates);
  hipLaunchKernelGGL(k_rec, dim3(8), dim3(1024), 0, stream, g_gates, g_u0, g_hs);
  // layer 1
  hipLaunchKernelGGL((k_gates<1>), dim3(500, 8), dim3(256), 0, stream, g_hs, g_w1, b1, g_gates);
  hipLaunchKernelGGL(k_rec, dim3(8), dim3(1024), 0, stream, g_gates, g_u1, g_hs);
  // layer 2
  hipLaunchKernelGGL((k_gates<1>), dim3(500, 8), dim3(256), 0, stream, g_hs, g_w2, b2, g_gates);
  hipLaunchKernelGGL(k_rec, dim3(8), dim3(1024), 0, stream, g_gates, g_u2, g_hs);

  // FC + pack
  hipLaunchKernelGGL(k_fc, dim3(64, 32), dim3(256), 0, stream, g_hs, g_wfc, bfc, lens, g_offs, out);
}

// Round 2
// 4907.820 us; speedup vs baseline: 6.5402x; 6.5402x over previous
//
#include <hip/hip_runtime.h>

typedef _Float16 f16;
typedef _Float16 half8 __attribute__((ext_vector_type(8)));
typedef float f32x4 __attribute__((ext_vector_type(4)));

__device__ inline float frcp(float x) {
#if __has_builtin(__builtin_amdgcn_rcpf)
  return __builtin_amdgcn_rcpf(x);
#else
  return 1.0f / x;
#endif
}
__device__ inline float fexp2(float x) {
#if __has_builtin(__builtin_amdgcn_exp2f)
  return __builtin_amdgcn_exp2f(x);
#else
  return exp2f(x);
#endif
}

__device__ inline unsigned int pack2f16(float a, float b) {
  f16 x = (f16)a, y = (f16)b;
  unsigned short ux = __builtin_bit_cast(unsigned short, x);
  unsigned short uy = __builtin_bit_cast(unsigned short, y);
  return (unsigned int)ux | ((unsigned int)uy << 16);
}

// ---------------- small prep kernels ----------------

__global__ void k_cvt(const float* __restrict__ s, f16* __restrict__ d, int n) {
  int i = blockIdx.x * 256 + threadIdx.x;
  if (i < n) d[i] = (f16)s[i];
}

__global__ void k_zero(unsigned int* __restrict__ p, int n) {
  int i = blockIdx.x * 256 + threadIdx.x;
  if (i < n) p[i] = 0u;
}

// w0 [1024][89] -> padded f16 [1024][96]
__global__ void k_w0pad(const float* __restrict__ w0, f16* __restrict__ d) {
  int i = blockIdx.x * 256 + threadIdx.x;
  if (i >= 1024 * 96) return;
  int row = i / 96, c = i % 96;
  d[i] = (c < 89) ? (f16)w0[row * 89 + c] : (f16)0.f;
}

// xb0 f16 [128][500][96]: s<64: x[s][t][f]; s>=64: x[s-64][499-t][f]; pad f>=89 with 0
__global__ void k_xb0(const float* __restrict__ x, f16* __restrict__ d) {
  int i = blockIdx.x * 256 + threadIdx.x;
  if (i >= 128 * 500 * 96) return;
  int f = i % 96;
  int t = (i / 96) % 500;
  int s = i / (96 * 500);
  float v = 0.f;
  if (f < 89) {
    if (s < 64) v = x[((size_t)s * 500 + t) * 89 + f];
    else        v = x[((size_t)(s - 64) * 500 + (499 - t)) * 89 + f];
  }
  d[i] = (f16)v;
}

__global__ void k_offs(const int* __restrict__ lens, int* __restrict__ offs) {
  if (threadIdx.x == 0 && blockIdx.x == 0) {
    int s = 0;
    for (int i = 0; i < 64; ++i) { offs[i] = s; s += lens[i]; }
  }
}

// ---------------- gates GEMM ----------------
// gates[t][s][n] = bias[n] + sum_k X(s,t,k) * W[n][k],  f16 out, layout [T][128][1024]
template <int MODE>
__global__ __launch_bounds__(256) void k_gates(const f16* __restrict__ Aw,
                                               const f16* __restrict__ W16,
                                               const float* __restrict__ bias,
                                               f16* __restrict__ gates) {
  constexpr int KW = MODE ? 1024 : 96;
  const int t = blockIdx.x;
  const int nb = blockIdx.y * 128;
  const int tid = threadIdx.x;
  const int w = tid >> 6, l = tid & 63, c = l & 15, rg = l >> 4;
  const int wr = w >> 1, wc = w & 1;

  __shared__ f16 As[128 * 40];
  __shared__ f16 Bs[128 * 40];

  f32x4 acc[4][4] = {};

  const int srow = tid >> 1;
  const int seg = (tid & 1) * 16;

  for (int kb = 0; kb < KW; kb += 32) {
    const f16* pa;
    if (MODE == 0) {
      pa = Aw + ((size_t)srow * 500 + t) * 96 + kb + seg;
    } else {
      int f0 = kb + seg;
      int half = f0 >> 9;
      int col = f0 & 511;
      int s = srow;
      int seq, time;
      if (s < 64) { seq = half ? 64 + s : s;  time = half ? 499 - t : t; }
      else        { seq = half ? s : s - 64;  time = half ? t : 499 - t; }
      pa = Aw + ((size_t)seq * 500 + time) * 512 + col;
    }
    const f16* pb = W16 + (size_t)(nb + srow) * KW + kb + seg;
    half8 a0 = *(const half8*)pa;
    half8 a1 = *(const half8*)(pa + 8);
    half8 b0 = *(const half8*)pb;
    half8 b1 = *(const half8*)(pb + 8);
    __syncthreads();
    *(half8*)&As[srow * 40 + seg] = a0;
    *(half8*)&As[srow * 40 + seg + 8] = a1;
    *(half8*)&Bs[srow * 40 + seg] = b0;
    *(half8*)&Bs[srow * 40 + seg + 8] = b1;
    __syncthreads();
    half8 aF[4], bF[4];
#pragma unroll
    for (int i = 0; i < 4; ++i)
      aF[i] = *(const half8*)&As[(wr * 64 + i * 16 + c) * 40 + rg * 8];
#pragma unroll
    for (int j = 0; j < 4; ++j)
      bF[j] = *(const half8*)&Bs[(wc * 64 + j * 16 + c) * 40 + rg * 8];
#pragma unroll
    for (int i = 0; i < 4; ++i)
#pragma unroll
      for (int j = 0; j < 4; ++j)
        acc[i][j] = __builtin_amdgcn_mfma_f32_16x16x32_f16(aF[i], bF[j], acc[i][j], 0, 0, 0);
  }

#pragma unroll
  for (int j = 0; j < 4; ++j) {
    int n = nb + wc * 64 + j * 16 + c;
    float bj = bias[n];
#pragma unroll
    for (int i = 0; i < 4; ++i) {
#pragma unroll
      for (int r = 0; r < 4; ++r) {
        int m = wr * 64 + i * 16 + rg * 4 + r;
        gates[((size_t)t * 128 + m) * 1024 + n] = (f16)(acc[i][j][r] + bj);
      }
    }
  }
}

// ---------------- recurrence (column-split, 64 WGs) ----------------
// 64 WGs = 8 seq-groups (sg = blockIdx&7, 16 seqs) x 8 col-groups (cg, 64 hidden cols).
// 4 waves/WG; wave w owns hidden tile hcol = cg*64 + w*16: gate cols a=[hcol,+16),
// z=[512+hcol,+16). U B-frags (32 x half8 = 128 VGPR) register-resident, statically
// indexed. h exchanged per step via agent-coherent (MALL) f32 buffer hx[2][128][512],
// staged to XOR-swizzled LDS. Sync: monotone arrival counter per sg; target 32*t.
__global__ __launch_bounds__(256, 1) void k_rec(const f16* __restrict__ gates,
                                                const f16* __restrict__ U,    // [1024][512] f16
                                                f16* __restrict__ hs,         // [128][500][512] f16
                                                float* __restrict__ hx,       // [2][128][512] f32
                                                unsigned int* __restrict__ cnt) {
  const int sg = blockIdx.x & 7, cg = blockIdx.x >> 3;
  const int tid = threadIdx.x;
  const int l = tid & 63, w = tid >> 6, c = l & 15, rg = l >> 4;
  const int s0 = sg * 16;
  const int hcol = cg * 64 + w * 16;
  const int an0 = hcol, zn0 = 512 + hcol;

  __shared__ f16 hlds[16 * 512];  // h tile [16 rows][512 cols], XOR-swizzled

  // U fragments: B[k][n] = U[n][k]; lane holds n = n0 + c, k = kt*32 + rg*8 + e
  half8 ua[16], uz[16];
#pragma unroll
  for (int kt = 0; kt < 16; ++kt) {
    ua[kt] = *(const half8*)(U + (size_t)(an0 + c) * 512 + kt * 32 + rg * 8);
    uz[kt] = *(const half8*)(U + (size_t)(zn0 + c) * 512 + kt * 32 + rg * 8);
  }

  float hold[4] = {0.f, 0.f, 0.f, 0.f};
  unsigned int* cflag = cnt + sg * 32;   // 128B-spaced per-sg counters

  // preload gates t=0
  f16 ga[4], gz[4];
  {
    const f16* gb = gates + ((size_t)0 * 128 + s0 + rg * 4) * 1024;
#pragma unroll
    for (int r = 0; r < 4; ++r) { ga[r] = gb[r * 1024 + an0 + c]; gz[r] = gb[r * 1024 + zn0 + c]; }
  }

  for (int t = 0; t < 500; ++t) {
    // 1. prefetch next step's gates (normal cached loads; fly during poll)
    int tn = (t + 1 < 500) ? t + 1 : 499;
    f16 gna[4], gnz[4];
    {
      const f16* gb = gates + ((size_t)tn * 128 + s0 + rg * 4) * 1024;
#pragma unroll
      for (int r = 0; r < 4; ++r) { gna[r] = gb[r * 1024 + an0 + c]; gnz[r] = gb[r * 1024 + zn0 + c]; }
    }

    // 2. wait until all 32 waves of this seq-group finished step t-1
    if (t) {
      const unsigned int tgt = 32u * (unsigned int)t;
      int guard = 0;
      while (__hip_atomic_load(cflag, __ATOMIC_RELAXED, __HIP_MEMORY_SCOPE_AGENT) < tgt) {
        if (++guard > (1 << 17)) break;  // safety valve: terminate instead of hang
      }
      asm volatile("" ::: "memory");
    }

    // 3. cooperative stage h^t -> LDS (coherent loads bypass stale L1/L2)
    {
      const int p0 = t & 1;
      const unsigned long long* hsrc =
          (const unsigned long long*)(hx + (size_t)p0 * 65536 + (size_t)s0 * 512);
      unsigned long long tmp[16];
#pragma unroll
      for (int n = 0; n < 16; ++n)
        tmp[n] = __hip_atomic_load(hsrc + n * 256 + tid, __ATOMIC_RELAXED, __HIP_MEMORY_SCOPE_AGENT);
#pragma unroll
      for (int n = 0; n < 16; ++n) {
        float lo = __builtin_bit_cast(float, (unsigned int)tmp[n]);
        float hi = __builtin_bit_cast(float, (unsigned int)(tmp[n] >> 32));
        int elem = (n * 512 + tid * 2) ^ ((n & 7) << 3);   // row n, col pair 2*tid
        *(unsigned int*)&hlds[elem] = pack2f16(lo, hi);
      }
    }
    __syncthreads();

    // 4. MFMA: acc = gates + h @ U^T  (A-frag: row=c, k=kt*32+rg*8+e)
    f32x4 acc_a, acc_z;
#pragma unroll
    for (int r = 0; r < 4; ++r) { acc_a[r] = (float)ga[r]; acc_z[r] = (float)gz[r]; }
#pragma unroll
    for (int kt = 0; kt < 16; ++kt) {
      int elem = (c * 512 + kt * 32 + rg * 8) ^ ((c & 7) << 3);
      half8 aF = *(const half8*)&hlds[elem];
      acc_a = __builtin_amdgcn_mfma_f32_16x16x32_f16(aF, ua[kt], acc_a, 0, 0, 0);
      acc_z = __builtin_amdgcn_mfma_f32_16x16x32_f16(aF, uz[kt], acc_z, 0, 0, 0);
    }

    // 5. gating (lane-local; C layout: col=c, row=rg*4+r) + stores
    const int p1 = (t & 1) ^ 1;
    float* hdst = hx + (size_t)p1 * 65536;
#pragma unroll
    for (int r = 0; r < 4; ++r) {
      float av = acc_a[r];
      float zv = acc_z[r];
      float zs = frcp(1.f + fexp2(-1.44269504f * zv));   // sigmoid(z)
      float u2 = fexp2(2.88539008f * av);
      float th = 1.f - 2.f * frcp(u2 + 1.f);             // tanh(a)
      float hn = th + zs * (hold[r] - th);
      hold[r] = hn;
      int srow = rg * 4 + r;
      __hip_atomic_store(&hdst[(size_t)(s0 + srow) * 512 + hcol + c], hn,
                         __ATOMIC_RELAXED, __HIP_MEMORY_SCOPE_AGENT);
      hs[((size_t)(s0 + srow) * 500 + t) * 512 + hcol + c] = (f16)hn;
    }

    // 6. arrive: stores done -> bump counter (one lane per wave)
    asm volatile("s_waitcnt vmcnt(0)" ::: "memory");
    if (l == 0)
      __hip_atomic_fetch_add(cflag, 1u, __ATOMIC_RELAXED, __HIP_MEMORY_SCOPE_AGENT);

#pragma unroll
    for (int r = 0; r < 4; ++r) { ga[r] = gna[r]; gz[r] = gnz[r]; }
  }
}

// ---------------- FC + pack ----------------
__global__ __launch_bounds__(256) void k_fc(const f16* __restrict__ hs,
                                            const f16* __restrict__ wfc,   // [72][1024] f16
                                            const float* __restrict__ bfc,
                                            const int* __restrict__ lens,
                                            const int* __restrict__ offs,
                                            float* __restrict__ out) {
  const int b = blockIdx.x, chunk = blockIdx.y;
  const int tid = threadIdx.x;
  __shared__ f16 X[16][1032];
#pragma unroll
  for (int ii = 0; ii < 8; ++ii) {
    int sg = ii * 256 + tid;
    int row = sg >> 7;
    int f = (sg & 127) * 8;
    int t = chunk * 16 + row;
    int tt = t < 500 ? t : 499;
    int half = f >> 9, col = f & 511;
    int seq = half ? 64 + b : b;
    int time = half ? 499 - tt : tt;
    *(half8*)&X[row][f] = *(const half8*)&hs[((size_t)seq * 500 + time) * 512 + col];
  }
  __syncthreads();
  int row = tid >> 4, og = tid & 15;
  int t = chunk * 16 + row;
  int len = lens[b];
  float acc[5];
#pragma unroll
  for (int j = 0; j < 5; ++j) {
    int o = j * 16 + og;
    acc[j] = (o < 72) ? bfc[o] : 0.f;
  }
  for (int k8 = 0; k8 < 128; ++k8) {
    half8 x8 = *(const half8*)&X[row][k8 * 8];
    float xf[8];
#pragma unroll
    for (int e = 0; e < 8; ++e) xf[e] = (float)x8[e];
#pragma unroll
    for (int j = 0; j < 5; ++j) {
      int o = j * 16 + og;
      int oc = o < 72 ? o : 0;
      half8 w8 = *(const half8*)&wfc[(size_t)oc * 1024 + k8 * 8];
#pragma unroll
      for (int e = 0; e < 8; ++e) acc[j] += xf[e] * (float)w8[e];
    }
  }
  if (t < 500 && t < len) {
    size_t base = ((size_t)offs[b] + t) * 72;
#pragma unroll
    for (int j = 0; j < 5; ++j) {
      int o = j * 16 + og;
      if (o < 72) out[base + o] = acc[j];
    }
  }
}

// ---------------- launcher ----------------

extern "C" void kernel_launch(void* const* d_in, const int* in_sizes, int n_in,
                              void* d_out, int out_size, void* d_ws, size_t ws_size,
                              hipStream_t stream) {
  const float* batch = (const float*)d_in[0];
  const int*   lens  = (const int*)d_in[1];
  const float* w0 = (const float*)d_in[2];
  const float* b0 = (const float*)d_in[3];
  const float* u0 = (const float*)d_in[4];
  const float* w1 = (const float*)d_in[5];
  const float* b1 = (const float*)d_in[6];
  const float* u1 = (const float*)d_in[7];
  const float* w2 = (const float*)d_in[8];
  const float* b2 = (const float*)d_in[9];
  const float* u2 = (const float*)d_in[10];
  const float* wfc = (const float*)d_in[11];
  const float* bfc = (const float*)d_in[12];
  float* out = (float*)d_out;

  char* ws = (char*)d_ws;
  const size_t GATES_OFF = 0;                  // [500][128][1024] f16 = 131,072,000
  const size_t HS_OFF    = 131072000;          // [128][500][512]  f16 =  65,536,000
  const size_t XB0_OFF   = 196608000;          // [128][500][96]   f16 =  12,288,000
  const size_t W0P_OFF   = 208896000;          // [1024][96]  f16
  const size_t W1_OFF    = 209092608;          // [1024][1024] f16
  const size_t W2_OFF    = 211189760;
  const size_t U0_OFF    = 213286912;          // [1024][512] f16
  const size_t U1_OFF    = 214335488;
  const size_t U2_OFF    = 215384064;
  const size_t WFC_OFF   = 216432640;          // [72][1024] f16
  const size_t OFFS_OFF  = 216580096;          // 64 ints
  const size_t HX_OFF    = 216581120;          // [2][128][512] f32 = 524,288
  const size_t CNT_OFF   = 217105408;          // 8 x 32 uints (128B spacing)

  f16* g_gates = (f16*)(ws + GATES_OFF);
  f16* g_hs    = (f16*)(ws + HS_OFF);
  f16* g_xb0   = (f16*)(ws + XB0_OFF);
  f16* g_w0p   = (f16*)(ws + W0P_OFF);
  f16* g_w1    = (f16*)(ws + W1_OFF);
  f16* g_w2    = (f16*)(ws + W2_OFF);
  f16* g_u0    = (f16*)(ws + U0_OFF);
  f16* g_u1    = (f16*)(ws + U1_OFF);
  f16* g_u2    = (f16*)(ws + U2_OFF);
  f16* g_wfc   = (f16*)(ws + WFC_OFF);
  int* g_offs  = (int*)(ws + OFFS_OFF);
  float* g_hx  = (float*)(ws + HX_OFF);
  unsigned int* g_cnt = (unsigned int*)(ws + CNT_OFF);
  unsigned int* g_sync0 = (unsigned int*)(ws + HX_OFF);  // zero hx+cnt together
  const int ZERO_N = (524288 + 1024) / 4;                // dwords

  hipLaunchKernelGGL(k_offs, dim3(1), dim3(64), 0, stream, lens, g_offs);

  auto cvt = [&](const float* s, f16* d, int n) {
    hipLaunchKernelGGL(k_cvt, dim3((n + 255) / 256), dim3(256), 0, stream, s, d, n);
  };
  cvt(w1, g_w1, 1024 * 1024);
  cvt(w2, g_w2, 1024 * 1024);
  cvt(u0, g_u0, 1024 * 512);
  cvt(u1, g_u1, 1024 * 512);
  cvt(u2, g_u2, 1024 * 512);
  cvt(wfc, g_wfc, 72 * 1024);
  hipLaunchKernelGGL(k_w0pad, dim3((1024 * 96 + 255) / 256), dim3(256), 0, stream, w0, g_w0p);
  hipLaunchKernelGGL(k_xb0, dim3((128 * 500 * 96 + 255) / 256), dim3(256), 0, stream, batch, g_xb0);

  // layer 0
  hipLaunchKernelGGL((k_gates<0>), dim3(500, 8), dim3(256), 0, stream, g_xb0, g_w0p, b0, g_gates);
  hipLaunchKernelGGL(k_zero, dim3((ZERO_N + 255) / 256), dim3(256), 0, stream, g_sync0, ZERO_N);
  hipLaunchKernelGGL(k_rec, dim3(64), dim3(256), 0, stream, g_gates, g_u0, g_hs, g_hx, g_cnt);
  // layer 1
  hipLaunchKernelGGL((k_gates<1>), dim3(500, 8), dim3(256), 0, stream, g_hs, g_w1, b1, g_gates);
  hipLaunchKernelGGL(k_zero, dim3((ZERO_N + 255) / 256), dim3(256), 0, stream, g_sync0, ZERO_N);
  hipLaunchKernelGGL(k_rec, dim3(64), dim3(256), 0, stream, g_gates, g_u1, g_hs, g_hx, g_cnt);
  // layer 2
  hipLaunchKernelGGL((k_gates<1>), dim3(500, 8), dim3(256), 0, stream, g_hs, g_w2, b2, g_gates);
  hipLaunchKernelGGL(k_zero, dim3((ZERO_N + 255) / 256), dim3(256), 0, stream, g_sync0, ZERO_N);
  hipLaunchKernelGGL(k_rec, dim3(64), dim3(256), 0, stream, g_gates, g_u2, g_hs, g_hx, g_cnt);

  // FC + pack
  hipLaunchKernelGGL(k_fc, dim3(64, 32), dim3(256), 0, stream, g_hs, g_wfc, bfc, lens, g_offs, out);
}